// Round 4
// baseline (478.783 us; speedup 1.0000x reference)
//
#include <hip/hip_runtime.h>
#include <math.h>

#define NN 8192
#define DD 256
#define TOPK 64
#define CAP 96            // survivor capacity per row
#define CCAP 256          // candidate capacity for exact select
#define NEGVAL (-1000000000.0f)

typedef _Float16 f16;
typedef f16  f16x8 __attribute__((ext_vector_type(8)));
typedef float f32x4 __attribute__((ext_vector_type(4)));

// ---------------------------------------------------------------------------
// f32 NT GEMM for QKV projections (8192x256x256): C = A @ B^T + bias
// ---------------------------------------------------------------------------
__global__ __launch_bounds__(256)
void gemm_nt_f32(const float* __restrict__ A, const float* __restrict__ B,
                 float* __restrict__ C, int ldc, const float* __restrict__ bias)
{
  __shared__ float As[32][128];
  __shared__ float Bs[32][128];
  const int t  = threadIdx.x;
  const int tm = t & 15;
  const int tn = t >> 4;
  const int m0 = blockIdx.x * 128;
  const int n0 = blockIdx.y * 128;

  float acc[8][8];
#pragma unroll
  for (int i = 0; i < 8; ++i)
#pragma unroll
    for (int j = 0; j < 8; ++j) acc[i][j] = 0.0f;

  for (int k0 = 0; k0 < DD; k0 += 32) {
#pragma unroll
    for (int i = 0; i < 4; ++i) {
      int idx = t + i * 256;
      int row = idx >> 3;
      int c4  = (idx & 7) << 2;
      float4 av = *(const float4*)(A + (size_t)(m0 + row) * DD + k0 + c4);
      float4 bv = *(const float4*)(B + (size_t)(n0 + row) * DD + k0 + c4);
      As[c4 + 0][row] = av.x; As[c4 + 1][row] = av.y;
      As[c4 + 2][row] = av.z; As[c4 + 3][row] = av.w;
      Bs[c4 + 0][row] = bv.x; Bs[c4 + 1][row] = bv.y;
      Bs[c4 + 2][row] = bv.z; Bs[c4 + 3][row] = bv.w;
    }
    __syncthreads();
#pragma unroll
    for (int kk = 0; kk < 32; ++kk) {
      float a[8], b[8];
      *(float4*)&a[0] = *(const float4*)&As[kk][tm * 4];
      *(float4*)&a[4] = *(const float4*)&As[kk][64 + tm * 4];
      *(float4*)&b[0] = *(const float4*)&Bs[kk][tn * 4];
      *(float4*)&b[4] = *(const float4*)&Bs[kk][64 + tn * 4];
#pragma unroll
      for (int i = 0; i < 8; ++i)
#pragma unroll
        for (int j = 0; j < 8; ++j)
          acc[i][j] = fmaf(a[i], b[j], acc[i][j]);
    }
    __syncthreads();
  }

#pragma unroll
  for (int gi = 0; gi < 2; ++gi)
#pragma unroll
    for (int r = 0; r < 4; ++r) {
      const int grow = m0 + gi * 64 + tm * 4 + r;
#pragma unroll
      for (int gj = 0; gj < 2; ++gj) {
        const int gcol0 = n0 + gj * 64 + tn * 4;
        float v[4];
#pragma unroll
        for (int c = 0; c < 4; ++c)
          v[c] = acc[gi * 4 + r][gj * 4 + c] + (bias ? bias[gcol0 + c] : 0.0f);
        *(float4*)(C + (size_t)grow * ldc + gcol0) =
            make_float4(v[0], v[1], v[2], v[3]);
      }
    }
}

// ---------------------------------------------------------------------------
// Split Q,K (f32) into f16 hi/lo, K-dim-768 layout:
//   Qs[row] = [Qhi | Qhi | Qlo],  Ks[row] = [Khi | Klo | Khi]
// sum over 768 = Qhi*Khi + Qhi*Klo + Qlo*Khi (lo*lo dropped, ~2^-22)
// ---------------------------------------------------------------------------
__global__ __launch_bounds__(256)
void cvt_hilo(const float* __restrict__ Q, const float* __restrict__ Kf,
              f16* __restrict__ Qs, f16* __restrict__ Ks)
{
  const size_t i = (size_t)blockIdx.x * 256 + threadIdx.x;
  const int r = (int)(i >> 8);
  const int c = (int)(i & 255);
  float q = Q[i];
  f16 qh = (f16)q;
  f16 ql = (f16)(q - (float)qh);
  Qs[(size_t)r * 768 + c]       = qh;
  Qs[(size_t)r * 768 + 256 + c] = qh;
  Qs[(size_t)r * 768 + 512 + c] = ql;
  float k = Kf[i];
  f16 kh = (f16)k;
  f16 kl = (f16)(k - (float)kh);
  Ks[(size_t)r * 768 + c]       = kh;
  Ks[(size_t)r * 768 + 256 + c] = kl;
  Ks[(size_t)r * 768 + 512 + c] = kh;
}

// ---------------------------------------------------------------------------
// MFMA scores GEMM, v2:
//  + both-sides XOR swizzle (pre-swizzled global source for global_load_lds,
//    XOR'd ds_read_b128 addr) -> kills the 16-way bank conflict
//  + bijective XCD-chunked block swizzle (L2 locality for the K panel)
//  + LDS-transposed coalesced C store (aliases As/Bs; full 128B lines)
// ---------------------------------------------------------------------------
typedef __attribute__((address_space(1))) const void GV;
typedef __attribute__((address_space(3))) void LV;
__device__ __forceinline__ void gl_lds16(const void* g, void* l) {
  __builtin_amdgcn_global_load_lds((GV*)g, (LV*)l, 16, 0, 0);
}

__global__ __launch_bounds__(256)
void gemm_scores_f16(const f16* __restrict__ Aq, const f16* __restrict__ Bk,
                     float* __restrict__ C, const float* __restrict__ temp,
                     int rowOff)
{
  __shared__ __align__(16) char smem[32768];
  f16* As = (f16*)smem;                       // 128 rows x 64 f16 (16 KB)
  f16* Bs = (f16*)(smem + 16384);             // 128 rows x 64 f16 (16 KB)
  float (*Cs)[132] = (float (*)[132])smem;    // 32 x 132 f32, aliases As/Bs

  const int t  = threadIdx.x;
  const int l  = t & 63;
  const int w  = t >> 6;
  const int wr = w >> 1;
  const int wc = w & 1;

  // bijective XCD-chunked block swizzle (T1, m204)
  const int gx = gridDim.x;
  const int nwg = gx * gridDim.y;
  const int flat = blockIdx.y * gx + blockIdx.x;
  const int qq = nwg >> 3, rr = nwg & 7;
  const int xcd = flat & 7, off2 = flat >> 3;
  const int bas = (xcd < rr) ? xcd * (qq + 1) : rr * (qq + 1) + (xcd - rr) * qq;
  const int id  = bas + off2;
  const int m0 = (id % gx) * 128;
  const int n0 = (id / gx) * 128;

  f32x4 acc[4][4];
#pragma unroll
  for (int m = 0; m < 4; ++m)
#pragma unroll
    for (int n = 0; n < 4; ++n) acc[m][n] = (f32x4){0.f, 0.f, 0.f, 0.f};

  const int lr = l >> 3;                 // staging row within 8-row segment
  const int ls = l & 7;                  // staging 16B slot
  const int lk = ((ls ^ lr) & 7) * 8;    // pre-swizzled global k-offset (f16)
  const int fr = l & 15;                 // fragment row
  const int fg = l >> 4;                 // fragment k-group
  const int swz = (fr & 7) * 8;          // read-side XOR (f16 units)

  for (int k0 = 0; k0 < 768; k0 += 64) {
    __syncthreads();
#pragma unroll
    for (int i = 0; i < 4; ++i) {
      const int seg = w * 4 + i;
      gl_lds16(Aq + (size_t)(m0 + seg * 8 + lr) * 768 + k0 + lk, &As[seg * 512]);
      gl_lds16(Bk + (size_t)(n0 + seg * 8 + lr) * 768 + k0 + lk, &Bs[seg * 512]);
    }
    __syncthreads();
#pragma unroll
    for (int kk = 0; kk < 2; ++kk) {
      f16x8 af[4], bf[4];
#pragma unroll
      for (int m = 0; m < 4; ++m)
        af[m] = *(const f16x8*)&As[(wr * 64 + m * 16 + fr) * 64 + ((kk * 32 + fg * 8) ^ swz)];
#pragma unroll
      for (int n = 0; n < 4; ++n)
        bf[n] = *(const f16x8*)&Bs[(wc * 64 + n * 16 + fr) * 64 + ((kk * 32 + fg * 8) ^ swz)];
#pragma unroll
      for (int m = 0; m < 4; ++m)
#pragma unroll
        for (int n = 0; n < 4; ++n)
          acc[m][n] = __builtin_amdgcn_mfma_f32_16x16x32_f16(af[m], bf[n], acc[m][n], 0, 0, 0);
    }
  }

  const float invts = 1.0f / (temp[0] * 16.0f);

  // LDS-transposed coalesced store: 4 passes of 32 rows x 128 cols
#pragma unroll
  for (int p = 0; p < 4; ++p) {
    __syncthreads();
    if (wr == (p >> 1)) {
      const int h = p & 1;
#pragma unroll
      for (int mm = 0; mm < 2; ++mm) {
        const int m = h * 2 + mm;
#pragma unroll
        for (int n = 0; n < 4; ++n)
#pragma unroll
          for (int j = 0; j < 4; ++j)
            Cs[mm * 16 + fg * 4 + j][wc * 64 + n * 16 + fr] = acc[m][n][j] * invts;
      }
    }
    __syncthreads();
#pragma unroll
    for (int k = 0; k < 4; ++k) {
      const int c  = t + k * 256;        // 0..1023 float4 slots
      const int r32 = c >> 5;
      const int c4  = (c & 31) * 4;
      const int lrow = m0 + p * 32 + r32;          // row within Sc chunk
      float4 vv = *(const float4*)&Cs[r32][c4];
      const int dq = (rowOff + lrow) - (n0 + c4);  // diagonal position
      if (dq >= 0 && dq < 4) ((float*)&vv)[dq] = NEGVAL;
      *(float4*)(C + (size_t)lrow * NN + n0 + c4) = vv;
    }
  }
}

// ---------------------------------------------------------------------------
// topk_softmax v2 (proven in R3): row in registers, histogram select,
// exact 64th-largest among candidates, deterministic compaction.
// ---------------------------------------------------------------------------
__global__ __launch_bounds__(256)
void topk_softmax2(const float* __restrict__ Sc, int rowOff,
                   float* __restrict__ wts, int* __restrict__ idx,
                   int* __restrict__ cnt)
{
  __shared__ unsigned hist[256];
  __shared__ int      pfx[256];
  __shared__ float    candv[CCAP];
  __shared__ float    pb[CAP];
  __shared__ int      jb[CAP];
  __shared__ float    wmax[4], wsum[4];
  __shared__ int      sB, candn;
  __shared__ unsigned uT;

  const int t = threadIdx.x;
  const int l = t & 63;
  const int w = t >> 6;
  const int grow = rowOff + blockIdx.x;
  const float* srow = Sc + (size_t)blockIdx.x * NN;

  float v[32];
#pragma unroll
  for (int c = 0; c < 8; ++c) {
    float4 f = *(const float4*)(srow + ((size_t)c * 256 + t) * 4);
    v[c * 4 + 0] = f.x; v[c * 4 + 1] = f.y; v[c * 4 + 2] = f.z; v[c * 4 + 3] = f.w;
  }

  float lm = -3.0e38f;
#pragma unroll
  for (int r = 0; r < 32; ++r) lm = fmaxf(lm, v[r]);
#pragma unroll
  for (int off = 32; off; off >>= 1) lm = fmaxf(lm, __shfl_xor(lm, off));
  if (l == 0) wmax[w] = lm;
  __syncthreads();
  const float m = fmaxf(fmaxf(wmax[0], wmax[1]), fmaxf(wmax[2], wmax[3]));

  float lo = m - 2.5f;
  int B = -1;
  for (int iter = 0; iter < 8; ++iter) {
    hist[t] = 0u;
    __syncthreads();
    const float invw = 256.0f / (m - lo);
#pragma unroll
    for (int r = 0; r < 32; ++r) {
      float s = v[r];
      if (s >= lo) {
        int b = (int)((s - lo) * invw);
        b = (b > 255) ? 255 : b;
        atomicAdd(&hist[b], 1u);
      }
    }
    __syncthreads();
    for (int st = 1; st < 256; st <<= 1) {
      unsigned add = (t + st < 256) ? hist[t + st] : 0u;
      __syncthreads();
      hist[t] += add;
      __syncthreads();
    }
    if (hist[0] >= TOPK) {
      unsigned here = hist[t];
      unsigned nxt = (t == 255) ? 0u : hist[t + 1];
      if (here >= TOPK && nxt < TOPK) sB = t;
      __syncthreads();
      B = sB;
      break;
    }
    __syncthreads();
    lo = m - 2.5f * (float)(2 << iter);
  }
  if (B < 0) B = 0;

  if (t == 0) candn = 0;
  __syncthreads();
  {
    const float invw = 256.0f / (m - lo);
#pragma unroll
    for (int r = 0; r < 32; ++r) {
      float s = v[r];
      if (s >= lo) {
        int b = (int)((s - lo) * invw);
        b = (b > 255) ? 255 : b;
        if (b >= B) {
          int p = atomicAdd(&candn, 1);
          if (p < CCAP) candv[p] = s;
        }
      }
    }
  }
  __syncthreads();
  const int L = (candn < CCAP) ? candn : CCAP;

  if (t == 0) uT = 0xFFFFFFFFu;
  __syncthreads();
  for (int i = t; i < L; i += 256) {
    float vi = candv[i];
    int g = 0;
    for (int j = 0; j < L; ++j) g += (candv[j] > vi) ? 1 : 0;
    if (g <= TOPK - 1) {
      unsigned ub = __float_as_uint(vi);
      unsigned u = (ub & 0x80000000u) ? ~ub : (ub | 0x80000000u);
      atomicMin(&uT, u);
    }
  }
  __syncthreads();
  const unsigned uth = uT;
  const float T = __uint_as_float((uth & 0x80000000u) ? (uth & 0x7FFFFFFFu) : ~uth);

  int myc = 0;
#pragma unroll
  for (int r = 0; r < 32; ++r) myc += (v[r] >= T) ? 1 : 0;
  pfx[t] = myc;
  __syncthreads();
  for (int st = 1; st < 256; st <<= 1) {
    int add = (t >= st) ? pfx[t - st] : 0;
    __syncthreads();
    pfx[t] += add;
    __syncthreads();
  }
  int base = pfx[t] - myc;
  const int total = pfx[255];
#pragma unroll
  for (int r = 0; r < 32; ++r) {
    if (v[r] >= T) {
      if (base < CAP) {
        pb[base] = __expf(v[r] - m);
        jb[base] = ((r >> 2) * 256 + t) * 4 + (r & 3);
      }
      ++base;
    }
  }
  __syncthreads();
  const int L2 = (total < CAP) ? total : CAP;

  float ps = 0.0f;
  for (int i = t; i < L2; i += 256) ps += pb[i];
#pragma unroll
  for (int off = 32; off; off >>= 1) ps += __shfl_xor(ps, off);
  if (l == 0) wsum[w] = ps;
  __syncthreads();
  const float inv = 1.0f / (wsum[0] + wsum[1] + wsum[2] + wsum[3]);
  for (int i = t; i < L2; i += 256) {
    wts[(size_t)grow * CAP + i] = pb[i] * inv;
    idx[(size_t)grow * CAP + i] = jb[i];
  }
  if (t == 0) cnt[grow] = L2;
}

// ---------------------------------------------------------------------------
__global__ __launch_bounds__(256)
void sparse_av(const float* __restrict__ V, const float* __restrict__ wts,
               const int* __restrict__ idx, const int* __restrict__ cnt,
               float* __restrict__ out)
{
  __shared__ float wl[CAP];
  __shared__ int   jl[CAP];
  const int t = threadIdx.x;
  const int row = blockIdx.x;
  const int L = cnt[row];
  if (t < CAP && t < L) {
    wl[t] = wts[(size_t)row * CAP + t];
    jl[t] = idx[(size_t)row * CAP + t];
  }
  __syncthreads();
  float acc = 0.0f;
  for (int i = 0; i < L; ++i)
    acc = fmaf(wl[i], V[(size_t)jl[i] * DD + t], acc);
  out[(size_t)row * DD + t] = acc;
}

// ---------------------------------------------------------------------------
extern "C" void kernel_launch(void* const* d_in, const int* in_sizes, int n_in,
                              void* d_out, int out_size, void* d_ws, size_t ws_size,
                              hipStream_t stream)
{
  const float* X    = (const float*)d_in[0];
  const float* Wq   = (const float*)d_in[1];
  const float* bq   = (const float*)d_in[2];
  const float* Wk   = (const float*)d_in[3];
  const float* bk   = (const float*)d_in[4];
  const float* Wv   = (const float*)d_in[5];
  const float* bv   = (const float*)d_in[6];
  const float* temp = (const float*)d_in[7];
  float* out = (float*)d_out;
  float* ws  = (float*)d_ws;

  const size_t avail = ws_size / sizeof(float);

  const size_t szQK  = (size_t)NN * DD;
  const size_t szHL  = (size_t)NN * 768 / 2;
  const size_t szWts = (size_t)NN * CAP;
  const size_t szIdx = (size_t)NN * CAP;
  const size_t szCnt = NN;
  const size_t fixed = 2 * szQK + 2 * szHL + szWts + szIdx + szCnt;

  size_t o = 0;
  float* Kbuf = ws + o; o += szQK;
  float* Qbuf = ws + o; o += szQK;
  f16*   Qs   = (f16*)(ws + o); o += szHL;
  f16*   Ks   = (f16*)(ws + o); o += szHL;
  float* wts  = ws + o; o += szWts;
  int*   idxb = (int*)(ws + o); o += szIdx;
  int*   cntb = (int*)(ws + o); o += szCnt;

  if (avail <= fixed + (size_t)128 * NN) return;
  int CR = (int)(((avail - fixed) / NN) / 128) * 128;
  if (CR > NN) CR = NN;
  float* Sc = ws + o;

  dim3 blk(256);

  gemm_nt_f32<<<dim3(NN/128, DD/128), blk, 0, stream>>>(X, Wk, Kbuf, DD, bk);
  gemm_nt_f32<<<dim3(NN/128, DD/128), blk, 0, stream>>>(X, Wq, Qbuf, DD, bq);
  cvt_hilo<<<dim3((NN * DD) / 256), blk, 0, stream>>>(Qbuf, Kbuf, Qs, Ks);
  float* Vbuf = Qbuf;
  gemm_nt_f32<<<dim3(NN/128, DD/128), blk, 0, stream>>>(X, Wv, Vbuf, DD, bv);

  for (int r0 = 0; r0 < NN; r0 += CR) {
    const int rows = (NN - r0 < CR) ? (NN - r0) : CR;
    gemm_scores_f16<<<dim3(rows/128, NN/128), blk, 0, stream>>>(
        Qs + (size_t)r0 * 768, Ks, Sc, temp, r0);
    topk_softmax2<<<dim3(rows), blk, 0, stream>>>(Sc, r0, wts, idxb, cntb);
  }

  sparse_av<<<dim3(NN), blk, 0, stream>>>(Vbuf, wts, idxb, cntb, out);
}